// Round 8
// baseline (1545.037 us; speedup 1.0000x reference)
//
#include <hip/hip_runtime.h>
#include <hip/hip_bf16.h>
#include <math.h>

// PSI_Full: B=8, S=4096, D=512. fp32 in/out.
// Round 14: B-operand off the LDS-DMA path. Model: staging rate is pinned at
// ~4-5.4 TB/s (~10 B/cyc/CU) across ALL schedules/occupancies (R6-R13) ->
// the global_load_lds path itself saturates; time tracks DMA bytes. Fix:
// load B fragments directly global->VGPR (16B/lane short8, L2-broadcast:
// WTo1 4.2MB x64 row-blocks reuse, WTp2/WTo2/WTcat smaller). Halves DMA
// bytes, halves LDS (16KB), drops B barriers. Bit-identical numerics (same
// values, same MFMA order). A staging: simple single-buffer 2-barrier loop
// (dbuf/counted-vmcnt measured null 3x). scan_excl_par kept (neutral-ok).

#define BB 8
#define SS 4096
#define DD 512
#define NCH 128
#define CHS 32        // SS / NCH
#define BSL 2         // batch per slice
#define NSL 4
#define NPROJ 2560    // 5 * DD

typedef __attribute__((ext_vector_type(8))) short short8;
typedef __attribute__((ext_vector_type(4))) float f32x4;
typedef __hip_bfloat16 bf16;

__device__ inline void load_lds16(const bf16* g, bf16* l) {
  __builtin_amdgcn_global_load_lds(
      (const __attribute__((address_space(1))) void*)g,
      (__attribute__((address_space(3))) void*)l, 16, 0, 0);
}

// ---------------------------------------------------------------------------
// bf16 MFMA GEMM: C[M,N] = act(A[M,K](lda=Alda) @ WT[N,K]^T + bias[N]) (+resid)
// act: 0 none, 1 sig, 2 sig*5, 3 gelu(exact), 9 = fused-proj table by col>>9.
// Tile 128x128, BK=64, 256 threads = 4 waves (2x2), each wave 4x4 of 16x16.
// A staged via global_load_lds (16KB single buffer); B fragments loaded
// DIRECTLY global->VGPR (per-lane 16B, L2-resident weight panels).
// K multiple of 64. XCD swizzle (gy==64): XCD c8 gets row band 8*c8..8*c8+7.
// ---------------------------------------------------------------------------
__global__ __launch_bounds__(256) void gemm_mfma(
    const bf16* __restrict__ A, int Alda,
    const bf16* __restrict__ WT,            // [N][K]
    const float* __restrict__ bias,
    const float* __restrict__ resid,        // fp32 [M][N] or null
    void* __restrict__ C, int K, int N, int act, int outBf16)
{
  __shared__ bf16 As[8192];  // [kseg 0..7][row 0..127][8]
  const int tid = threadIdx.x;
  int bx, by;
  if (gridDim.y == 64) {
    const int l = blockIdx.y * gridDim.x + blockIdx.x;
    const int c8 = l & 7, i = l >> 3;
    by = (c8 << 3) + (i & 7);     // row-block: XCD-contiguous band
    bx = i >> 3;                  // col-block
  } else { bx = blockIdx.x; by = blockIdx.y; }
  const int row0 = by << 7;
  const int col0 = bx << 7;
  const int lane = tid & 63;
  const int wv = tid >> 6;
  const int wr = (wv >> 1) << 6;
  const int wc = (wv & 1) << 6;
  const int q  = lane >> 4;
  const int mn = lane & 15;

  int eact = act;
  if (act == 9) { const int tbl[5] = {0, 1, 2, 3, 0}; eact = tbl[col0 >> 9]; }

  f32x4 acc[4][4];
#pragma unroll
  for (int i = 0; i < 4; ++i)
#pragma unroll
    for (int j = 0; j < 4; ++j) acc[i][j] = (f32x4){0.f, 0.f, 0.f, 0.f};

  const int srow = tid & 127;
  const bf16* Ag = A + (size_t)(row0 + srow) * Alda + ((tid >> 7) << 3);
  bf16* Asl = As + tid * 8;

  // Per-lane B base: row (col0 + wc + mn), k-offset q*8.
  // Fragment t, sub-step j at k0 reads 16B at Bw + t*16*K + k0 + j*32.
  const bf16* Bw = WT + (size_t)(col0 + wc + mn) * K + (q << 3);
  const size_t BK16 = (size_t)K << 4;   // 16 rows stride

  for (int k0 = 0; k0 < K; k0 += 64) {
    __syncthreads();
#pragma unroll
    for (int i = 0; i < 4; ++i)
      load_lds16(Ag + k0 + i * 16, Asl + i * 2048);
    __syncthreads();
    const short8* Av = (const short8*)As;   // index = kseg*128 + row
#pragma unroll
    for (int j = 0; j < 2; ++j) {           // two K=32 sub-steps
      short8 af[4], bfr[4];
      const int ks = (j << 2) + q;
#pragma unroll
      for (int t = 0; t < 4; ++t)
        af[t] = Av[ks * 128 + wr + t * 16 + mn];
#pragma unroll
      for (int t = 0; t < 4; ++t)
        bfr[t] = *(const short8*)(Bw + (size_t)t * BK16 + k0 + (j << 5));
#pragma unroll
      for (int mt = 0; mt < 4; ++mt)
#pragma unroll
        for (int nt = 0; nt < 4; ++nt)
          acc[mt][nt] = __builtin_amdgcn_mfma_f32_16x16x32_bf16(
              af[mt], bfr[nt], acc[mt][nt], 0, 0, 0);
    }
  }

  // C/D layout: col = lane&15, row = quad*4 + reg.
#pragma unroll
  for (int mt = 0; mt < 4; ++mt) {
#pragma unroll
    for (int nt = 0; nt < 4; ++nt) {
      const int gcol = col0 + wc + nt * 16 + mn;
      const float bcol = bias[gcol];
#pragma unroll
      for (int r = 0; r < 4; ++r) {
        const int grow = row0 + wr + mt * 16 + q * 4 + r;
        const size_t o = (size_t)grow * N + gcol;
        float v = acc[mt][nt][r] + bcol;
        if (eact == 1)      v = 1.f / (1.f + __expf(-v));
        else if (eact == 2) v = 5.f / (1.f + __expf(-v));
        else if (eact == 3) v = 0.5f * v * (1.f + erff(v * 0.70710678118654752f));
        if (resid) v += resid[o];
        if (outBf16) ((bf16*)C)[o] = __float2bfloat16(v);
        else         ((float*)C)[o] = v;
      }
    }
  }
}

// ---------------------------------------------------------------------------
__global__ __launch_bounds__(256) void wtrans(
    const float* __restrict__ W, bf16* __restrict__ WT, int K, int N)
{
  __shared__ float t[32][33];
  const int n0 = blockIdx.x << 5, k0 = blockIdx.y << 5;
  const int tx = threadIdx.x & 31, ty = threadIdx.x >> 5;
  for (int i = ty; i < 32; i += 8)
    t[i][tx] = W[(size_t)(k0 + i) * N + n0 + tx];
  __syncthreads();
  for (int i = ty; i < 32; i += 8)
    WT[(size_t)(n0 + i) * K + k0 + tx] = __float2bfloat16(t[tx][i]);
}

__global__ __launch_bounds__(256) void castbf(
    const float* __restrict__ in, bf16* __restrict__ o, int n)
{
  const int i = (blockIdx.x * 256 + threadIdx.x) * 4;
  if (i < n) {
    const float4 v = *(const float4*)(in + i);
    o[i]     = __float2bfloat16(v.x);
    o[i + 1] = __float2bfloat16(v.y);
    o[i + 2] = __float2bfloat16(v.z);
    o[i + 3] = __float2bfloat16(v.w);
  }
}

// bias concat: 5 segments of 512 -> bcat[2560]
__global__ void bconcat(const float* b0, const float* b1, const float* b2,
                        const float* b3, const float* b4, float* bcat)
{
  const int d = threadIdx.x;
  const float* src[5] = {b0, b1, b2, b3, b4};
  bcat[blockIdx.x * DD + d] = src[blockIdx.x][d];
}

// ---------------------------------------------------------------------------
// Scans. proj row m: [omega|gate|mag|g1|qoff] bf16, stride NPROJ.
// phi_init in phib (bf16); running phi fp32 buffer.
// ---------------------------------------------------------------------------
__global__ __launch_bounds__(512) void scan_partialA(
    const bf16* __restrict__ proj, const float* __restrict__ iscale,
    float* __restrict__ pA)
{
  const int b = blockIdx.x >> 7;
  const int c = blockIdx.x & (NCH - 1);
  const int d = threadIdx.x;
  const float sc = fabsf(iscale[d]);
  size_t base = (((size_t)b * SS) + (size_t)c * CHS) * NPROJ + d;
  float acc = 0.f;
  for (int s = 0; s < CHS; ++s) {
    size_t idx = base + (size_t)s * NPROJ;
    acc = fmaf(__bfloat162float(proj[idx]) * __bfloat162float(proj[idx + DD]), sc, acc);
  }
  pA[((size_t)b * NCH + c) * DD + d] = acc;
}

// Exclusive prefix over c (NCH=128 chunks) for each (plane g, d).
// Grid: nplanes*DD blocks of 128 threads; thread c holds one chunk value.
// 2-wave Hillis-Steele: shfl_up within wave + wave0 total via LDS.
__global__ __launch_bounds__(128) void scan_excl_par(float* __restrict__ p)
{
  __shared__ float w0;
  const int g = blockIdx.x >> 9;       // plane index (DD=512=2^9)
  const int d = blockIdx.x & (DD - 1);
  const int c = threadIdx.x;           // 0..127
  const size_t idx = ((size_t)g * NCH + c) * DD + d;
  const float v = p[idx];
  float s = v;
#pragma unroll
  for (int o = 1; o < 64; o <<= 1) {
    float u = __shfl_up(s, o);
    if ((c & 63) >= o) s += u;
  }
  if (c == 63) w0 = s;
  __syncthreads();
  if (c >= 64) s += w0;
  p[idx] = s - v;                      // exclusive
}

__global__ __launch_bounds__(512) void scan_stageB(
    const bf16* __restrict__ proj, const bf16* __restrict__ xh,
    const bf16* __restrict__ phib, const float* __restrict__ iscale,
    float* __restrict__ phi, const float* __restrict__ pA,
    float* __restrict__ pRIM)
{
  const int b = blockIdx.x >> 7;
  const int c = blockIdx.x & (NCH - 1);
  const int d = threadIdx.x;
  const float sc = fabsf(iscale[d]);
  float accA = pA[((size_t)b * NCH + c) * DD + d];
  float aR = 0.f, aI = 0.f, aM = 0.f;
  const size_t m0 = (size_t)b * SS + (size_t)c * CHS;
  for (int s = 0; s < CHS; ++s) {
    const size_t m = m0 + s;
    const size_t pj = m * NPROJ + d;
    accA = fmaf(__bfloat162float(proj[pj]) * __bfloat162float(proj[pj + DD]), sc, accA);
    float ph = __bfloat162float(phib[m * DD + d]) + accA;
    phi[m * DD + d] = ph;
    float cp, sp;
    __sincosf(ph, &sp, &cp);
    float mg = __bfloat162float(proj[pj + 2 * DD]);
    float wc = mg * __bfloat162float(xh[m * DD + d]);
    aR = fmaf(wc, cp, aR);
    aI = fmaf(wc, sp, aI);
    aM += mg;
  }
  size_t pidx = ((size_t)b * NCH + c) * DD + d;
  const size_t stride = (size_t)BSL * NCH * DD;
  pRIM[pidx] = aR;
  pRIM[pidx + stride] = aI;
  pRIM[pidx + 2 * stride] = aM;
}

__global__ __launch_bounds__(512) void scan_final(
    const bf16* __restrict__ proj, const bf16* __restrict__ xh,
    const float* __restrict__ phi, const float* __restrict__ pRIM,
    const float* __restrict__ ln_g, const float* __restrict__ ln_b,
    bf16* __restrict__ ctxn)
{
  __shared__ float red[16];
  const int b = blockIdx.x >> 7;
  const int c = blockIdx.x & (NCH - 1);
  const int d = threadIdx.x;
  size_t pidx = ((size_t)b * NCH + c) * DD + d;
  const size_t stride = (size_t)BSL * NCH * DD;
  float aR = pRIM[pidx];
  float aI = pRIM[pidx + stride];
  float aM = pRIM[pidx + 2 * stride];
  const float g0 = ln_g[d],        e0 = ln_b[d];
  const float g1 = ln_g[DD + d],   e1 = ln_b[DD + d];
  const float g2 = ln_g[2*DD + d], e2 = ln_b[2*DD + d];
  const float g3 = ln_g[3*DD + d], e3 = ln_b[3*DD + d];
  const int lane = threadIdx.x & 63;
  const int wv = threadIdx.x >> 6;
  const size_t m0 = (size_t)b * SS + (size_t)c * CHS;
  for (int s = 0; s < CHS; ++s) {
    const size_t m = m0 + s;
    const size_t pj = m * NPROJ + d;
    float ph = phi[m * DD + d];
    float xv = __bfloat162float(xh[m * DD + d]);
    float mg = __bfloat162float(proj[pj + 2 * DD]);
    float cp, sp;
    __sincosf(ph, &sp, &cp);
    float wc = mg * xv;
    aR = fmaf(wc, cp, aR);
    aI = fmaf(wc, sp, aI);
    aM += mg;
    float inv = 1.f / sqrtf(aM + 1e-8f);
    float mr = aR * inv, mi = aI * inv;
    float pq = ph + __bfloat162float(proj[pj + 4 * DD]);
    float cq, sq;
    __sincosf(pq, &sq, &cq);
    float rr = fmaf(mr, cq, mi * sq);
    float ri = fmaf(mi, cq, -(mr * sq));
    float v0 = xv * cp, v1 = xv * sp;
    float lsum = (v0 + v1) + (rr + ri);
    float lsq  = fmaf(v0, v0, fmaf(v1, v1, fmaf(rr, rr, ri * ri)));
#pragma unroll
    for (int o = 32; o > 0; o >>= 1) {
      lsum += __shfl_down(lsum, o);
      lsq  += __shfl_down(lsq, o);
    }
    if (lane == 0) { red[wv] = lsum; red[8 + wv] = lsq; }
    __syncthreads();
    float tsum = red[0] + red[1] + red[2] + red[3] + red[4] + red[5] + red[6] + red[7];
    float tsq  = red[8] + red[9] + red[10] + red[11] + red[12] + red[13] + red[14] + red[15];
    __syncthreads();
    const float invN = 1.f / 2048.f;
    float mean = tsum * invN;
    float var  = tsq * invN - mean * mean;
    float rstd = rsqrtf(var + 1e-5f);
    size_t row = m * (4 * DD);
    ctxn[row + d]        = __float2bfloat16(fmaf((v0 - mean) * rstd, g0, e0));
    ctxn[row + DD + d]   = __float2bfloat16(fmaf((v1 - mean) * rstd, g1, e1));
    ctxn[row + 2*DD + d] = __float2bfloat16(fmaf((rr - mean) * rstd, g2, e2));
    ctxn[row + 3*DD + d] = __float2bfloat16(fmaf((ri - mean) * rstd, g3, e3));
  }
}

// ---------------------------------------------------------------------------
extern "C" void kernel_launch(void* const* d_in, const int* in_sizes, int n_in,
                              void* d_out, int out_size, void* d_ws, size_t ws_size,
                              hipStream_t stream)
{
  const float* x       = (const float*)d_in[0];
  const float* W_omega = (const float*)d_in[1];
  const float* b_omega = (const float*)d_in[2];
  const float* W_p1    = (const float*)d_in[3];
  const float* b_p1    = (const float*)d_in[4];
  const float* W_p2    = (const float*)d_in[5];
  const float* b_p2    = (const float*)d_in[6];
  const float* W_gate  = (const float*)d_in[7];
  const float* b_gate  = (const float*)d_in[8];
  const float* iscale  = (const float*)d_in[9];
  const float* W_mag   = (const float*)d_in[10];
  const float* b_mag   = (const float*)d_in[11];
  const float* W_qoff  = (const float*)d_in[12];
  const float* b_qoff  = (const float*)d_in[13];
  const float* ln_g    = (const float*)d_in[14];
  const float* ln_b    = (const float*)d_in[15];
  const float* W_o1    = (const float*)d_in[16];
  const float* b_o1    = (const float*)d_in[17];
  const float* W_o2    = (const float*)d_in[18];
  const float* b_o2    = (const float*)d_in[19];
  float* out = (float*)d_out;

  // Workspace (~119 MB). Es = BSL*SS*DD = 4.19M; Ms = 8192 rows/slice.
  const size_t Es = (size_t)BSL * SS * DD;
  const size_t Ms = (size_t)BSL * SS;
  char* p = (char*)d_ws;
  bf16* proj  = (bf16*)p; p += Ms * NPROJ * 2;            // 41.9 MB
  bf16* phib  = (bf16*)p; p += Es * 2;                    //  8.4 MB
  float* phi  = (float*)p; p += Es * 4;                   // 16.8 MB
  bf16* xh    = (bf16*)p; p += Es * 2;                    //  8.4 MB
  bf16* ctxn  = (bf16*)p; p += 4 * Es * 2;                // 33.5 MB
  float* pA   = (float*)p; p += (size_t)BSL * NCH * DD * 4;
  float* pRIM = (float*)p; p += 3 * (size_t)BSL * NCH * DD * 4;
  float* bcat = (float*)p; p += NPROJ * 4;
  bf16* WTcat = (bf16*)p; p += (size_t)NPROJ * DD * 2;    //  2.6 MB
  bf16* WTp2  = (bf16*)p; p += (size_t)DD * DD * 2;
  bf16* WTo1  = (bf16*)p; p += (size_t)2048 * 1024 * 2;   //  4.2 MB
  bf16* WTo2  = (bf16*)p; p += (size_t)1024 * 512 * 2;
  bf16* hh    = proj;                                     // [8192,1024] overlay

  dim3 tb(256);
  const size_t WD = (size_t)DD * DD;
  wtrans<<<dim3(16, 16), tb, 0, stream>>>(W_omega, WTcat,          DD, DD);
  wtrans<<<dim3(16, 16), tb, 0, stream>>>(W_gate,  WTcat + WD,     DD, DD);
  wtrans<<<dim3(16, 16), tb, 0, stream>>>(W_mag,   WTcat + 2 * WD, DD, DD);
  wtrans<<<dim3(16, 16), tb, 0, stream>>>(W_p1,    WTcat + 3 * WD, DD, DD);
  wtrans<<<dim3(16, 16), tb, 0, stream>>>(W_qoff,  WTcat + 4 * WD, DD, DD);
  wtrans<<<dim3(16, 16), tb, 0, stream>>>(W_p2,    WTp2, DD, DD);
  wtrans<<<dim3(32, 64), tb, 0, stream>>>(W_o1,    WTo1, 4 * DD, 2 * DD);
  wtrans<<<dim3(16, 32), tb, 0, stream>>>(W_o2,    WTo2, 2 * DD, DD);
  bconcat<<<5, DD, 0, stream>>>(b_omega, b_gate, b_mag, b_p1, b_qoff, bcat);

  const dim3 gP(NPROJ / 128, Ms / 128);        // (20,64)
  const dim3 gD(DD / 128, Ms / 128);           // (4,64)
  const dim3 gO1((2 * DD) / 128, Ms / 128);    // (8,64)

  for (int sl = 0; sl < NSL; ++sl) {
    const float* xs = x + sl * Es;
    float* outs = out + sl * Es;
    castbf<<<(int)(Es / 1024), tb, 0, stream>>>(xs, xh, (int)Es);
    // fused projections + p2
    gemm_mfma<<<gP, tb, 0, stream>>>(xh, DD, WTcat, bcat, nullptr, proj, DD, NPROJ, 9, 1);
    gemm_mfma<<<gD, tb, 0, stream>>>(proj + 3 * DD, NPROJ, WTp2, b_p2, nullptr, phib, DD, DD, 0, 1);
    // scans
    scan_partialA<<<BSL * NCH, 512, 0, stream>>>(proj, iscale, pA);
    scan_excl_par<<<BSL * DD, 128, 0, stream>>>(pA);
    scan_stageB<<<BSL * NCH, 512, 0, stream>>>(proj, xh, phib, iscale, phi, pA, pRIM);
    scan_excl_par<<<3 * BSL * DD, 128, 0, stream>>>(pRIM);
    scan_final<<<BSL * NCH, 512, 0, stream>>>(proj, xh, phi, pRIM, ln_g, ln_b, ctxn);
    // output MLP
    gemm_mfma<<<gO1, tb, 0, stream>>>(ctxn, 4 * DD, WTo1, b_o1, nullptr, hh, 4 * DD, 2 * DD, 3, 1);
    gemm_mfma<<<gD, tb, 0, stream>>>(hh, 2 * DD, WTo2, b_o2, xs, outs, 2 * DD, DD, 0, 0);
  }
}

// Round 9
// 1265.986 us; speedup vs baseline: 1.2204x; 1.2204x over previous
//
#include <hip/hip_runtime.h>
#include <hip/hip_bf16.h>
#include <math.h>

// PSI_Full: B=8, S=4096, D=512. fp32 in/out.
// Round 15: batch the slices. Evidence: our staging rate is 8.7 B/cyc/CU
// (o1) vs m97's 23 on the SAME instruction pattern/chip — the gap tracks
// blocks/CU (2 vs 3-4) and steady-state length, NOT schedule (R7-R9 null)
// or bytes (R10/R11 regressions were +50% traffic). The slices are
// independent; slicing exists only for workspace. Runtime-select batch
// size by ws_size: BSL=8 (~453MB) -> o1 grid 2048 (5/CU LDS-capped),
// proj 5120; BSL=4 (~231MB); else BSL=2 (current fallback). Zero added
// traffic, 4x fewer launches. GEMM = round-0 32KB single-buffer loop
// (64KB dbuf would cap 2/CU; measured equal anyway). R14's B-direct
// reverted (uncoalesced gather, +56%). Swizzle generalized (band=gy/8).

#define BB 8
#define SS 4096
#define DD 512
#define NCH 128
#define CHS 32        // SS / NCH
#define NPROJ 2560    // 5 * DD

typedef __attribute__((ext_vector_type(8))) short short8;
typedef __attribute__((ext_vector_type(4))) float f32x4;
typedef __hip_bfloat16 bf16;

__device__ inline void load_lds16(const bf16* g, bf16* l) {
  __builtin_amdgcn_global_load_lds(
      (const __attribute__((address_space(1))) void*)g,
      (__attribute__((address_space(3))) void*)l, 16, 0, 0);
}

// ---------------------------------------------------------------------------
// bf16 MFMA GEMM: C[M,N] = act(A[M,K](lda=Alda) @ WT[N,K]^T + bias[N]) (+resid)
// act: 0 none, 1 sig, 2 sig*5, 3 gelu(exact), 9 = fused-proj table by col>>9.
// Tile 128x128, BK=64, 256 threads = 4 waves (2x2), each wave 4x4 of 16x16.
// 32KB LDS -> 5 blocks/CU. K multiple of 64. XCD swizzle when gy%8==0:
// XCD c8 gets contiguous row band of gy/8 row-blocks (bijective).
// ---------------------------------------------------------------------------
__global__ __launch_bounds__(256) void gemm_mfma(
    const bf16* __restrict__ A, int Alda,
    const bf16* __restrict__ WT,            // [N][K]
    const float* __restrict__ bias,
    const float* __restrict__ resid,        // fp32 [M][N] or null
    void* __restrict__ C, int K, int N, int act, int outBf16)
{
  __shared__ bf16 As[8192];  // [kseg 0..7][row 0..127][8]
  __shared__ bf16 Bs[8192];
  const int tid = threadIdx.x;
  int bx, by;
  const int gy = gridDim.y;
  if ((gy & 7) == 0 && gy >= 8) {
    const int band = gy >> 3;
    const int l = blockIdx.y * gridDim.x + blockIdx.x;
    const int c8 = l & 7, i = l >> 3;
    by = c8 * band + (i % band);  // row-block: XCD-contiguous band
    bx = i / band;                // col-block
  } else { bx = blockIdx.x; by = blockIdx.y; }
  const int row0 = by << 7;
  const int col0 = bx << 7;
  const int lane = tid & 63;
  const int wv = tid >> 6;
  const int wr = (wv >> 1) << 6;
  const int wc = (wv & 1) << 6;
  const int q  = lane >> 4;
  const int mn = lane & 15;

  int eact = act;
  if (act == 9) { const int tbl[5] = {0, 1, 2, 3, 0}; eact = tbl[col0 >> 9]; }

  f32x4 acc[4][4];
#pragma unroll
  for (int i = 0; i < 4; ++i)
#pragma unroll
    for (int j = 0; j < 4; ++j) acc[i][j] = (f32x4){0.f, 0.f, 0.f, 0.f};

  const int srow = tid & 127;
  const bf16* Ag = A  + (size_t)(row0 + srow) * Alda + ((tid >> 7) << 3);
  const bf16* Bg = WT + (size_t)(col0 + srow) * K + ((tid >> 7) << 3);
  bf16* Asl = As + tid * 8;
  bf16* Bsl = Bs + tid * 8;

  for (int k0 = 0; k0 < K; k0 += 64) {
    __syncthreads();
#pragma unroll
    for (int i = 0; i < 4; ++i) {
      load_lds16(Ag + k0 + i * 16, Asl + i * 2048);
      load_lds16(Bg + k0 + i * 16, Bsl + i * 2048);
    }
    __syncthreads();
    const short8* Av = (const short8*)As;   // index = kseg*128 + row
    const short8* Bv = (const short8*)Bs;
#pragma unroll
    for (int j = 0; j < 2; ++j) {           // two K=32 sub-steps
      short8 af[4], bfr[4];
      const int ks = (j << 2) + q;
#pragma unroll
      for (int t = 0; t < 4; ++t) af[t]  = Av[ks * 128 + wr + t * 16 + mn];
#pragma unroll
      for (int t = 0; t < 4; ++t) bfr[t] = Bv[ks * 128 + wc + t * 16 + mn];
#pragma unroll
      for (int mt = 0; mt < 4; ++mt)
#pragma unroll
        for (int nt = 0; nt < 4; ++nt)
          acc[mt][nt] = __builtin_amdgcn_mfma_f32_16x16x32_bf16(
              af[mt], bfr[nt], acc[mt][nt], 0, 0, 0);
    }
  }

  // C/D layout: col = lane&15, row = quad*4 + reg.
#pragma unroll
  for (int mt = 0; mt < 4; ++mt) {
#pragma unroll
    for (int nt = 0; nt < 4; ++nt) {
      const int gcol = col0 + wc + nt * 16 + mn;
      const float bcol = bias[gcol];
#pragma unroll
      for (int r = 0; r < 4; ++r) {
        const int grow = row0 + wr + mt * 16 + q * 4 + r;
        const size_t o = (size_t)grow * N + gcol;
        float v = acc[mt][nt][r] + bcol;
        if (eact == 1)      v = 1.f / (1.f + __expf(-v));
        else if (eact == 2) v = 5.f / (1.f + __expf(-v));
        else if (eact == 3) v = 0.5f * v * (1.f + erff(v * 0.70710678118654752f));
        if (resid) v += resid[o];
        if (outBf16) ((bf16*)C)[o] = __float2bfloat16(v);
        else         ((float*)C)[o] = v;
      }
    }
  }
}

// ---------------------------------------------------------------------------
__global__ __launch_bounds__(256) void wtrans(
    const float* __restrict__ W, bf16* __restrict__ WT, int K, int N)
{
  __shared__ float t[32][33];
  const int n0 = blockIdx.x << 5, k0 = blockIdx.y << 5;
  const int tx = threadIdx.x & 31, ty = threadIdx.x >> 5;
  for (int i = ty; i < 32; i += 8)
    t[i][tx] = W[(size_t)(k0 + i) * N + n0 + tx];
  __syncthreads();
  for (int i = ty; i < 32; i += 8)
    WT[(size_t)(n0 + i) * K + k0 + tx] = __float2bfloat16(t[tx][i]);
}

__global__ __launch_bounds__(256) void castbf(
    const float* __restrict__ in, bf16* __restrict__ o, int n)
{
  const int i = (blockIdx.x * 256 + threadIdx.x) * 4;
  if (i < n) {
    const float4 v = *(const float4*)(in + i);
    o[i]     = __float2bfloat16(v.x);
    o[i + 1] = __float2bfloat16(v.y);
    o[i + 2] = __float2bfloat16(v.z);
    o[i + 3] = __float2bfloat16(v.w);
  }
}

// bias concat: 5 segments of 512 -> bcat[2560]
__global__ void bconcat(const float* b0, const float* b1, const float* b2,
                        const float* b3, const float* b4, float* bcat)
{
  const int d = threadIdx.x;
  const float* src[5] = {b0, b1, b2, b3, b4};
  bcat[blockIdx.x * DD + d] = src[blockIdx.x][d];
}

// ---------------------------------------------------------------------------
// Scans. proj row m: [omega|gate|mag|g1|qoff] bf16, stride NPROJ.
// phi_init in phib (bf16); running phi fp32 buffer. nb = batches this pass.
// ---------------------------------------------------------------------------
__global__ __launch_bounds__(512) void scan_partialA(
    const bf16* __restrict__ proj, const float* __restrict__ iscale,
    float* __restrict__ pA)
{
  const int b = blockIdx.x >> 7;
  const int c = blockIdx.x & (NCH - 1);
  const int d = threadIdx.x;
  const float sc = fabsf(iscale[d]);
  size_t base = (((size_t)b * SS) + (size_t)c * CHS) * NPROJ + d;
  float acc = 0.f;
  for (int s = 0; s < CHS; ++s) {
    size_t idx = base + (size_t)s * NPROJ;
    acc = fmaf(__bfloat162float(proj[idx]) * __bfloat162float(proj[idx + DD]), sc, acc);
  }
  pA[((size_t)b * NCH + c) * DD + d] = acc;
}

// Exclusive prefix over c (NCH=128 chunks) for each (plane g, d).
// Grid: nplanes*DD blocks of 128 threads; thread c holds one chunk value.
__global__ __launch_bounds__(128) void scan_excl_par(float* __restrict__ p)
{
  __shared__ float w0;
  const int g = blockIdx.x >> 9;       // plane index (DD=512=2^9)
  const int d = blockIdx.x & (DD - 1);
  const int c = threadIdx.x;           // 0..127
  const size_t idx = ((size_t)g * NCH + c) * DD + d;
  const float v = p[idx];
  float s = v;
#pragma unroll
  for (int o = 1; o < 64; o <<= 1) {
    float u = __shfl_up(s, o);
    if ((c & 63) >= o) s += u;
  }
  if (c == 63) w0 = s;
  __syncthreads();
  if (c >= 64) s += w0;
  p[idx] = s - v;                      // exclusive
}

__global__ __launch_bounds__(512) void scan_stageB(
    const bf16* __restrict__ proj, const bf16* __restrict__ xh,
    const bf16* __restrict__ phib, const float* __restrict__ iscale,
    float* __restrict__ phi, const float* __restrict__ pA,
    float* __restrict__ pRIM, int nb)
{
  const int b = blockIdx.x >> 7;
  const int c = blockIdx.x & (NCH - 1);
  const int d = threadIdx.x;
  const float sc = fabsf(iscale[d]);
  float accA = pA[((size_t)b * NCH + c) * DD + d];
  float aR = 0.f, aI = 0.f, aM = 0.f;
  const size_t m0 = (size_t)b * SS + (size_t)c * CHS;
  for (int s = 0; s < CHS; ++s) {
    const size_t m = m0 + s;
    const size_t pj = m * NPROJ + d;
    accA = fmaf(__bfloat162float(proj[pj]) * __bfloat162float(proj[pj + DD]), sc, accA);
    float ph = __bfloat162float(phib[m * DD + d]) + accA;
    phi[m * DD + d] = ph;
    float cp, sp;
    __sincosf(ph, &sp, &cp);
    float mg = __bfloat162float(proj[pj + 2 * DD]);
    float wc = mg * __bfloat162float(xh[m * DD + d]);
    aR = fmaf(wc, cp, aR);
    aI = fmaf(wc, sp, aI);
    aM += mg;
  }
  size_t pidx = ((size_t)b * NCH + c) * DD + d;
  const size_t stride = (size_t)nb * NCH * DD;
  pRIM[pidx] = aR;
  pRIM[pidx + stride] = aI;
  pRIM[pidx + 2 * stride] = aM;
}

__global__ __launch_bounds__(512) void scan_final(
    const bf16* __restrict__ proj, const bf16* __restrict__ xh,
    const float* __restrict__ phi, const float* __restrict__ pRIM,
    const float* __restrict__ ln_g, const float* __restrict__ ln_b,
    bf16* __restrict__ ctxn, int nb)
{
  __shared__ float red[16];
  const int b = blockIdx.x >> 7;
  const int c = blockIdx.x & (NCH - 1);
  const int d = threadIdx.x;
  size_t pidx = ((size_t)b * NCH + c) * DD + d;
  const size_t stride = (size_t)nb * NCH * DD;
  float aR = pRIM[pidx];
  float aI = pRIM[pidx + stride];
  float aM = pRIM[pidx + 2 * stride];
  const float g0 = ln_g[d],        e0 = ln_b[d];
  const float g1 = ln_g[DD + d],   e1 = ln_b[DD + d];
  const float g2 = ln_g[2*DD + d], e2 = ln_b[2*DD + d];
  const float g3 = ln_g[3*DD + d], e3 = ln_b[3*DD + d];
  const int lane = threadIdx.x & 63;
  const int wv = threadIdx.x >> 6;
  const size_t m0 = (size_t)b * SS + (size_t)c * CHS;
  for (int s = 0; s < CHS; ++s) {
    const size_t m = m0 + s;
    const size_t pj = m * NPROJ + d;
    float ph = phi[m * DD + d];
    float xv = __bfloat162float(xh[m * DD + d]);
    float mg = __bfloat162float(proj[pj + 2 * DD]);
    float cp, sp;
    __sincosf(ph, &sp, &cp);
    float wc = mg * xv;
    aR = fmaf(wc, cp, aR);
    aI = fmaf(wc, sp, aI);
    aM += mg;
    float inv = 1.f / sqrtf(aM + 1e-8f);
    float mr = aR * inv, mi = aI * inv;
    float pq = ph + __bfloat162float(proj[pj + 4 * DD]);
    float cq, sq;
    __sincosf(pq, &sq, &cq);
    float rr = fmaf(mr, cq, mi * sq);
    float ri = fmaf(mi, cq, -(mr * sq));
    float v0 = xv * cp, v1 = xv * sp;
    float lsum = (v0 + v1) + (rr + ri);
    float lsq  = fmaf(v0, v0, fmaf(v1, v1, fmaf(rr, rr, ri * ri)));
#pragma unroll
    for (int o = 32; o > 0; o >>= 1) {
      lsum += __shfl_down(lsum, o);
      lsq  += __shfl_down(lsq, o);
    }
    if (lane == 0) { red[wv] = lsum; red[8 + wv] = lsq; }
    __syncthreads();
    float tsum = red[0] + red[1] + red[2] + red[3] + red[4] + red[5] + red[6] + red[7];
    float tsq  = red[8] + red[9] + red[10] + red[11] + red[12] + red[13] + red[14] + red[15];
    __syncthreads();
    const float invN = 1.f / 2048.f;
    float mean = tsum * invN;
    float var  = tsq * invN - mean * mean;
    float rstd = rsqrtf(var + 1e-5f);
    size_t row = m * (4 * DD);
    ctxn[row + d]        = __float2bfloat16(fmaf((v0 - mean) * rstd, g0, e0));
    ctxn[row + DD + d]   = __float2bfloat16(fmaf((v1 - mean) * rstd, g1, e1));
    ctxn[row + 2*DD + d] = __float2bfloat16(fmaf((rr - mean) * rstd, g2, e2));
    ctxn[row + 3*DD + d] = __float2bfloat16(fmaf((ri - mean) * rstd, g3, e3));
  }
}

// ---------------------------------------------------------------------------
static size_t ws_needed(int bsl) {
  const size_t Es = (size_t)bsl * SS * DD;
  const size_t Ms = (size_t)bsl * SS;
  return Ms * NPROJ * 2            // proj
       + Es * 2                    // phib
       + Es * 4                    // phi
       + Es * 2                    // xh
       + 4 * Es * 2                // ctxn
       + (size_t)bsl * NCH * DD * 4        // pA
       + 3 * (size_t)bsl * NCH * DD * 4    // pRIM
       + (size_t)NPROJ * 4                 // bcat
       + (size_t)NPROJ * DD * 2            // WTcat
       + (size_t)DD * DD * 2               // WTp2
       + (size_t)2048 * 1024 * 2           // WTo1
       + (size_t)1024 * 512 * 2;           // WTo2
}

extern "C" void kernel_launch(void* const* d_in, const int* in_sizes, int n_in,
                              void* d_out, int out_size, void* d_ws, size_t ws_size,
                              hipStream_t stream)
{
  const float* x       = (const float*)d_in[0];
  const float* W_omega = (const float*)d_in[1];
  const float* b_omega = (const float*)d_in[2];
  const float* W_p1    = (const float*)d_in[3];
  const float* b_p1    = (const float*)d_in[4];
  const float* W_p2    = (const float*)d_in[5];
  const float* b_p2    = (const float*)d_in[6];
  const float* W_gate  = (const float*)d_in[7];
  const float* b_gate  = (const float*)d_in[8];
  const float* iscale  = (const float*)d_in[9];
  const float* W_mag   = (const float*)d_in[10];
  const float* b_mag   = (const float*)d_in[11];
  const float* W_qoff  = (const float*)d_in[12];
  const float* b_qoff  = (const float*)d_in[13];
  const float* ln_g    = (const float*)d_in[14];
  const float* ln_b    = (const float*)d_in[15];
  const float* W_o1    = (const float*)d_in[16];
  const float* b_o1    = (const float*)d_in[17];
  const float* W_o2    = (const float*)d_in[18];
  const float* b_o2    = (const float*)d_in[19];
  float* out = (float*)d_out;

  // Runtime batch-size selection: biggest slice that fits the workspace.
  int bsl = 2;
  if (ws_size >= ws_needed(8)) bsl = 8;
  else if (ws_size >= ws_needed(4)) bsl = 4;
  const int nsl = BB / bsl;

  const size_t Es = (size_t)bsl * SS * DD;
  const size_t Ms = (size_t)bsl * SS;
  char* p = (char*)d_ws;
  bf16* proj  = (bf16*)p; p += Ms * NPROJ * 2;
  bf16* phib  = (bf16*)p; p += Es * 2;
  float* phi  = (float*)p; p += Es * 4;
  bf16* xh    = (bf16*)p; p += Es * 2;
  bf16* ctxn  = (bf16*)p; p += 4 * Es * 2;
  float* pA   = (float*)p; p += (size_t)bsl * NCH * DD * 4;
  float* pRIM = (float*)p; p += 3 * (size_t)bsl * NCH * DD * 4;
  float* bcat = (float*)p; p += NPROJ * 4;
  bf16* WTcat = (bf16*)p; p += (size_t)NPROJ * DD * 2;
  bf16* WTp2  = (bf16*)p; p += (size_t)DD * DD * 2;
  bf16* WTo1  = (bf16*)p; p += (size_t)2048 * 1024 * 2;
  bf16* WTo2  = (bf16*)p; p += (size_t)1024 * 512 * 2;
  bf16* hh    = proj;   // [Ms,1024] overlay (proj dead when o1 runs)

  dim3 tb(256);
  const size_t WD = (size_t)DD * DD;
  wtrans<<<dim3(16, 16), tb, 0, stream>>>(W_omega, WTcat,          DD, DD);
  wtrans<<<dim3(16, 16), tb, 0, stream>>>(W_gate,  WTcat + WD,     DD, DD);
  wtrans<<<dim3(16, 16), tb, 0, stream>>>(W_mag,   WTcat + 2 * WD, DD, DD);
  wtrans<<<dim3(16, 16), tb, 0, stream>>>(W_p1,    WTcat + 3 * WD, DD, DD);
  wtrans<<<dim3(16, 16), tb, 0, stream>>>(W_qoff,  WTcat + 4 * WD, DD, DD);
  wtrans<<<dim3(16, 16), tb, 0, stream>>>(W_p2,    WTp2, DD, DD);
  wtrans<<<dim3(32, 64), tb, 0, stream>>>(W_o1,    WTo1, 4 * DD, 2 * DD);
  wtrans<<<dim3(16, 32), tb, 0, stream>>>(W_o2,    WTo2, 2 * DD, DD);
  bconcat<<<5, DD, 0, stream>>>(b_omega, b_gate, b_mag, b_p1, b_qoff, bcat);

  const int gyM = (int)(Ms / 128);             // 64 / 128 / 256
  const dim3 gP(NPROJ / 128, gyM);
  const dim3 gD(DD / 128, gyM);
  const dim3 gO1((2 * DD) / 128, gyM);

  for (int sl = 0; sl < nsl; ++sl) {
    const float* xs = x + sl * Es;
    float* outs = out + sl * Es;
    castbf<<<(int)(Es / 1024), tb, 0, stream>>>(xs, xh, (int)Es);
    // fused projections + p2
    gemm_mfma<<<gP, tb, 0, stream>>>(xh, DD, WTcat, bcat, nullptr, proj, DD, NPROJ, 9, 1);
    gemm_mfma<<<gD, tb, 0, stream>>>(proj + 3 * DD, NPROJ, WTp2, b_p2, nullptr, phib, DD, DD, 0, 1);
    // scans
    scan_partialA<<<bsl * NCH, 512, 0, stream>>>(proj, iscale, pA);
    scan_excl_par<<<bsl * DD, 128, 0, stream>>>(pA);
    scan_stageB<<<bsl * NCH, 512, 0, stream>>>(proj, xh, phib, iscale, phi, pA, pRIM, bsl);
    scan_excl_par<<<3 * bsl * DD, 128, 0, stream>>>(pRIM);
    scan_final<<<bsl * NCH, 512, 0, stream>>>(proj, xh, phi, pRIM, ln_g, ln_b, ctxn, bsl);
    // output MLP
    gemm_mfma<<<gO1, tb, 0, stream>>>(ctxn, 4 * DD, WTo1, b_o1, nullptr, hh, 4 * DD, 2 * DD, 3, 1);
    gemm_mfma<<<gD, tb, 0, stream>>>(hh, 2 * DD, WTo2, b_o2, xs, outs, 2 * DD, DD, 0, 0);
  }
}

// Round 12
// 1095.403 us; speedup vs baseline: 1.4105x; 1.1557x over previous
//
#include <hip/hip_runtime.h>
#include <hip/hip_bf16.h>
#include <math.h>

// PSI_Full: B=8, S=4096, D=512. fp32 in/out.
// Round 18: same byte-reduction theory as R16/R17 (both died to container
// failures pre-launch; source audited correct 3x), re-expressed through a
// DIFFERENT source to break the correlated-flake coin flip: tile 128x256
// (was 256x128), 512 threads, 8 waves as 2Mx4N, wave-tile still 64x64
// (acc[4][4], same fragment values, same MFMA order -> bit-identical).
// Staged bytes/output (MT+NT)/(MT*NT) = -25% vs 128x128 (4.15 -> 3.11 GB
// ensemble) at the measured 15.6 B/cyc/CU staging rate. LDS 48KB
// (A 16KB + B 32KB). Runtime bsl selection (R15 win) + parallel scans kept.
// If this also container-fails => infra confirmed; resubmit R16 next.

#define BB 8
#define SS 4096
#define DD 512
#define NCH 128
#define CHS 32        // SS / NCH
#define NPROJ 2560    // 5 * DD

typedef __attribute__((ext_vector_type(8))) short short8;
typedef __attribute__((ext_vector_type(4))) float f32x4;
typedef __hip_bfloat16 bf16;

__device__ inline void load_lds16(const bf16* g, bf16* l) {
  __builtin_amdgcn_global_load_lds(
      (const __attribute__((address_space(1))) void*)g,
      (__attribute__((address_space(3))) void*)l, 16, 0, 0);
}

// ---------------------------------------------------------------------------
// bf16 MFMA GEMM: C[M,N] = act(A[M,K](lda=Alda) @ WT[N,K]^T + bias[N]) (+resid)
// act: 0 none, 1 sig, 2 sig*5, 3 gelu(exact), 9 = fused-proj table by col>>9.
// Tile 128x256, BK=64, 512 threads = 8 waves (2M x 4N), wave-tile 64x64.
// LDS 48KB (A 16KB + B 32KB) single buffer.
// K multiple of 64. M multiple of 128. N multiple of 256.
// XCD swizzle when gy%8==0: XCD c8 gets contiguous row band (bijective).
// ---------------------------------------------------------------------------
__global__ __launch_bounds__(512) void gemm_mfma(
    const bf16* __restrict__ A, int Alda,
    const bf16* __restrict__ WT,            // [N][K]
    const float* __restrict__ bias,
    const float* __restrict__ resid,        // fp32 [M][N] or null
    void* __restrict__ C, int K, int N, int act, int outBf16)
{
  __shared__ bf16 As[8192];   // [kseg 0..7][row 0..127][8]  16KB
  __shared__ bf16 Bs[16384];  // [kseg 0..7][row 0..255][8]  32KB
  const int tid = threadIdx.x;
  int bx, by;
  const int gy = gridDim.y;
  if ((gy & 7) == 0 && gy >= 8) {
    const int band = gy >> 3;
    const int l = blockIdx.y * gridDim.x + blockIdx.x;
    const int c8 = l & 7, i = l >> 3;
    by = c8 * band + (i % band);  // row-block: XCD-contiguous band
    bx = i / band;                // col-block
  } else { bx = blockIdx.x; by = blockIdx.y; }
  const int row0 = by << 7;       // 128-row tiles
  const int col0 = bx << 8;       // 256-col tiles
  const int lane = tid & 63;
  const int wv = tid >> 6;        // 0..7
  const int wr = (wv >> 2) << 6;  // 0,64
  const int wc = (wv & 3) << 6;   // 0,64,128,192
  const int q  = lane >> 4;
  const int mn = lane & 15;

  int eact = act;
  if (act == 9) { const int tbl[5] = {0, 1, 2, 3, 0}; eact = tbl[col0 >> 9]; }

  f32x4 acc[4][4];
#pragma unroll
  for (int i = 0; i < 4; ++i)
#pragma unroll
    for (int j = 0; j < 4; ++j) acc[i][j] = (f32x4){0.f, 0.f, 0.f, 0.f};

  // A staging: 16KB / 512 thr = 2 x 16B. kseg = 4i + (tid>>7), row = tid&127.
  // B staging: 32KB / 512 thr = 4 x 16B. kseg = 2i + (tid>>8), row = tid&255.
  const bf16* Ag = A  + (size_t)(row0 + (tid & 127)) * Alda + ((tid >> 7) << 3);
  const bf16* Bg = WT + (size_t)(col0 + (tid & 255)) * K + ((tid >> 8) << 3);
  bf16* Asl = As + tid * 8;
  bf16* Bsl = Bs + tid * 8;

  for (int k0 = 0; k0 < K; k0 += 64) {
    __syncthreads();
#pragma unroll
    for (int i = 0; i < 2; ++i)
      load_lds16(Ag + k0 + i * 32, Asl + i * 4096);
#pragma unroll
    for (int i = 0; i < 4; ++i)
      load_lds16(Bg + k0 + i * 16, Bsl + i * 4096);
    __syncthreads();
    const short8* Av = (const short8*)As;   // index = kseg*128 + row
    const short8* Bv = (const short8*)Bs;   // index = kseg*256 + row
#pragma unroll
    for (int j = 0; j < 2; ++j) {           // two K=32 sub-steps
      short8 af[4], bfr[4];
      const int ks = (j << 2) + q;
#pragma unroll
      for (int t = 0; t < 4; ++t) af[t]  = Av[ks * 128 + wr + t * 16 + mn];
#pragma unroll
      for (int t = 0; t < 4; ++t) bfr[t] = Bv[ks * 256 + wc + t * 16 + mn];
#pragma unroll
      for (int mt = 0; mt < 4; ++mt)
#pragma unroll
        for (int nt = 0; nt < 4; ++nt)
          acc[mt][nt] = __builtin_amdgcn_mfma_f32_16x16x32_bf16(
              af[mt], bfr[nt], acc[mt][nt], 0, 0, 0);
    }
  }

  // C/D layout: col = lane&15, row = quad*4 + reg.
#pragma unroll
  for (int mt = 0; mt < 4; ++mt) {
#pragma unroll
    for (int nt = 0; nt < 4; ++nt) {
      const int gcol = col0 + wc + nt * 16 + mn;
      const float bcol = bias[gcol];
#pragma unroll
      for (int r = 0; r < 4; ++r) {
        const int grow = row0 + wr + mt * 16 + q * 4 + r;
        const size_t o = (size_t)grow * N + gcol;
        float v = acc[mt][nt][r] + bcol;
        if (eact == 1)      v = 1.f / (1.f + __expf(-v));
        else if (eact == 2) v = 5.f / (1.f + __expf(-v));
        else if (eact == 3) v = 0.5f * v * (1.f + erff(v * 0.70710678118654752f));
        if (resid) v += resid[o];
        if (outBf16) ((bf16*)C)[o] = __float2bfloat16(v);
        else         ((float*)C)[o] = v;
      }
    }
  }
}

// ---------------------------------------------------------------------------
__global__ __launch_bounds__(256) void wtrans(
    const float* __restrict__ W, bf16* __restrict__ WT, int K, int N)
{
  __shared__ float t[32][33];
  const int n0 = blockIdx.x << 5, k0 = blockIdx.y << 5;
  const int tx = threadIdx.x & 31, ty = threadIdx.x >> 5;
  for (int i = ty; i < 32; i += 8)
    t[i][tx] = W[(size_t)(k0 + i) * N + n0 + tx];
  __syncthreads();
  for (int i = ty; i < 32; i += 8)
    WT[(size_t)(n0 + i) * K + k0 + tx] = __float2bfloat16(t[tx][i]);
}

__global__ __launch_bounds__(256) void castbf(
    const float* __restrict__ in, bf16* __restrict__ o, int n)
{
  const int i = (blockIdx.x * 256 + threadIdx.x) * 4;
  if (i < n) {
    const float4 v = *(const float4*)(in + i);
    o[i]     = __float2bfloat16(v.x);
    o[i + 1] = __float2bfloat16(v.y);
    o[i + 2] = __float2bfloat16(v.z);
    o[i + 3] = __float2bfloat16(v.w);
  }
}

// bias concat: 5 segments of 512 -> bcat[2560]
__global__ void bconcat(const float* b0, const float* b1, const float* b2,
                        const float* b3, const float* b4, float* bcat)
{
  const int d = threadIdx.x;
  const float* src[5] = {b0, b1, b2, b3, b4};
  bcat[blockIdx.x * DD + d] = src[blockIdx.x][d];
}

// ---------------------------------------------------------------------------
// Scans. proj row m: [omega|gate|mag|g1|qoff] bf16, stride NPROJ.
// phi_init in phib (bf16); running phi fp32 buffer. nb = batches this pass.
// ---------------------------------------------------------------------------
__global__ __launch_bounds__(512) void scan_partialA(
    const bf16* __restrict__ proj, const float* __restrict__ iscale,
    float* __restrict__ pA)
{
  const int b = blockIdx.x >> 7;
  const int c = blockIdx.x & (NCH - 1);
  const int d = threadIdx.x;
  const float sc = fabsf(iscale[d]);
  size_t base = (((size_t)b * SS) + (size_t)c * CHS) * NPROJ + d;
  float acc = 0.f;
  for (int s = 0; s < CHS; ++s) {
    size_t idx = base + (size_t)s * NPROJ;
    acc = fmaf(__bfloat162float(proj[idx]) * __bfloat162float(proj[idx + DD]), sc, acc);
  }
  pA[((size_t)b * NCH + c) * DD + d] = acc;
}

// Exclusive prefix over c (NCH=128 chunks) for each (plane g, d).
// Grid: nplanes*DD blocks of 128 threads; thread c holds one chunk value.
__global__ __launch_bounds__(128) void scan_excl_par(float* __restrict__ p)
{
  __shared__ float w0;
  const int g = blockIdx.x >> 9;       // plane index (DD=512=2^9)
  const int d = blockIdx.x & (DD - 1);
  const int c = threadIdx.x;           // 0..127
  const size_t idx = ((size_t)g * NCH + c) * DD + d;
  const float v = p[idx];
  float s = v;
#pragma unroll
  for (int o = 1; o < 64; o <<= 1) {
    float u = __shfl_up(s, o);
    if ((c & 63) >= o) s += u;
  }
  if (c == 63) w0 = s;
  __syncthreads();
  if (c >= 64) s += w0;
  p[idx] = s - v;                      // exclusive
}

__global__ __launch_bounds__(512) void scan_stageB(
    const bf16* __restrict__ proj, const bf16* __restrict__ xh,
    const bf16* __restrict__ phib, const float* __restrict__ iscale,
    float* __restrict__ phi, const float* __restrict__ pA,
    float* __restrict__ pRIM, int nb)
{
  const int b = blockIdx.x >> 7;
  const int c = blockIdx.x & (NCH - 1);
  const int d = threadIdx.x;
  const float sc = fabsf(iscale[d]);
  float accA = pA[((size_t)b * NCH + c) * DD + d];
  float aR = 0.f, aI = 0.f, aM = 0.f;
  const size_t m0 = (size_t)b * SS + (size_t)c * CHS;
  for (int s = 0; s < CHS; ++s) {
    const size_t m = m0 + s;
    const size_t pj = m * NPROJ + d;
    accA = fmaf(__bfloat162float(proj[pj]) * __bfloat162float(proj[pj + DD]), sc, accA);
    float ph = __bfloat162float(phib[m * DD + d]) + accA;
    phi[m * DD + d] = ph;
    float cp, sp;
    __sincosf(ph, &sp, &cp);
    float mg = __bfloat162float(proj[pj + 2 * DD]);
    float wc = mg * __bfloat162float(xh[m * DD + d]);
    aR = fmaf(wc, cp, aR);
    aI = fmaf(wc, sp, aI);
    aM += mg;
  }
  size_t pidx = ((size_t)b * NCH + c) * DD + d;
  const size_t stride = (size_t)nb * NCH * DD;
  pRIM[pidx] = aR;
  pRIM[pidx + stride] = aI;
  pRIM[pidx + 2 * stride] = aM;
}

__global__ __launch_bounds__(512) void scan_final(
    const bf16* __restrict__ proj, const bf16* __restrict__ xh,
    const float* __restrict__ phi, const float* __restrict__ pRIM,
    const float* __restrict__ ln_g, const float* __restrict__ ln_b,
    bf16* __restrict__ ctxn, int nb)
{
  __shared__ float red[16];
  const int b = blockIdx.x >> 7;
  const int c = blockIdx.x & (NCH - 1);
  const int d = threadIdx.x;
  size_t pidx = ((size_t)b * NCH + c) * DD + d;
  const size_t stride = (size_t)nb * NCH * DD;
  float aR = pRIM[pidx];
  float aI = pRIM[pidx + stride];
  float aM = pRIM[pidx + 2 * stride];
  const float g0 = ln_g[d],        e0 = ln_b[d];
  const float g1 = ln_g[DD + d],   e1 = ln_b[DD + d];
  const float g2 = ln_g[2*DD + d], e2 = ln_b[2*DD + d];
  const float g3 = ln_g[3*DD + d], e3 = ln_b[3*DD + d];
  const int lane = threadIdx.x & 63;
  const int wv = threadIdx.x >> 6;
  const size_t m0 = (size_t)b * SS + (size_t)c * CHS;
  for (int s = 0; s < CHS; ++s) {
    const size_t m = m0 + s;
    const size_t pj = m * NPROJ + d;
    float ph = phi[m * DD + d];
    float xv = __bfloat162float(xh[m * DD + d]);
    float mg = __bfloat162float(proj[pj + 2 * DD]);
    float cp, sp;
    __sincosf(ph, &sp, &cp);
    float wc = mg * xv;
    aR = fmaf(wc, cp, aR);
    aI = fmaf(wc, sp, aI);
    aM += mg;
    float inv = 1.f / sqrtf(aM + 1e-8f);
    float mr = aR * inv, mi = aI * inv;
    float pq = ph + __bfloat162float(proj[pj + 4 * DD]);
    float cq, sq;
    __sincosf(pq, &sq, &cq);
    float rr = fmaf(mr, cq, mi * sq);
    float ri = fmaf(mi, cq, -(mr * sq));
    float v0 = xv * cp, v1 = xv * sp;
    float lsum = (v0 + v1) + (rr + ri);
    float lsq  = fmaf(v0, v0, fmaf(v1, v1, fmaf(rr, rr, ri * ri)));
#pragma unroll
    for (int o = 32; o > 0; o >>= 1) {
      lsum += __shfl_down(lsum, o);
      lsq  += __shfl_down(lsq, o);
    }
    if (lane == 0) { red[wv] = lsum; red[8 + wv] = lsq; }
    __syncthreads();
    float tsum = red[0] + red[1] + red[2] + red[3] + red[4] + red[5] + red[6] + red[7];
    float tsq  = red[8] + red[9] + red[10] + red[11] + red[12] + red[13] + red[14] + red[15];
    __syncthreads();
    const float invN = 1.f / 2048.f;
    float mean = tsum * invN;
    float var  = tsq * invN - mean * mean;
    float rstd = rsqrtf(var + 1e-5f);
    size_t row = m * (4 * DD);
    ctxn[row + d]        = __float2bfloat16(fmaf((v0 - mean) * rstd, g0, e0));
    ctxn[row + DD + d]   = __float2bfloat16(fmaf((v1 - mean) * rstd, g1, e1));
    ctxn[row + 2*DD + d] = __float2bfloat16(fmaf((rr - mean) * rstd, g2, e2));
    ctxn[row + 3*DD + d] = __float2bfloat16(fmaf((ri - mean) * rstd, g3, e3));
  }
}

// ---------------------------------------------------------------------------
static size_t ws_needed(int bsl) {
  const size_t Es = (size_t)bsl * SS * DD;
  const size_t Ms = (size_t)bsl * SS;
  return Ms * NPROJ * 2            // proj
       + Es * 2                    // phib
       + Es * 4                    // phi
       + Es * 2                    // xh
       + 4 * Es * 2                // ctxn
       + (size_t)bsl * NCH * DD * 4        // pA
       + 3 * (size_t)bsl * NCH * DD * 4    // pRIM
       + (size_t)NPROJ * 4                 // bcat
       + (size_t)NPROJ * DD * 2            // WTcat
       + (size_t)DD * DD * 2               // WTp2
       + (size_t)2048 * 1024 * 2           // WTo1
       + (size_t)1024 * 512 * 2;           // WTo2
}

extern "C" void kernel_launch(void* const* d_in, const int* in_sizes, int n_in,
                              void* d_out, int out_size, void* d_ws, size_t ws_size,
                              hipStream_t stream)
{
  const float* x       = (const float*)d_in[0];
  const float* W_omega = (const float*)d_in[1];
  const float* b_omega = (const float*)d_in[2];
  const float* W_p1    = (const float*)d_in[3];
  const float* b_p1    = (const float*)d_in[4];
  const float* W_p2    = (const float*)d_in[5];
  const float* b_p2    = (const float*)d_in[6];
  const float* W_gate  = (const float*)d_in[7];
  const float* b_gate  = (const float*)d_in[8];
  const float* iscale  = (const float*)d_in[9];
  const float* W_mag   = (const float*)d_in[10];
  const float* b_mag   = (const float*)d_in[11];
  const float* W_qoff  = (const float*)d_in[12];
  const float* b_qoff  = (const float*)d_in[13];
  const float* ln_g    = (const float*)d_in[14];
  const float* ln_b    = (const float*)d_in[15];
  const float* W_o1    = (const float*)d_in[16];
  const float* b_o1    = (const float*)d_in[17];
  const float* W_o2    = (const float*)d_in[18];
  const float* b_o2    = (const float*)d_in[19];
  float* out = (float*)d_out;

  // Runtime batch-size selection: biggest slice that fits the workspace.
  int bsl = 2;
  if (ws_size >= ws_needed(8)) bsl = 8;
  else if (ws_size >= ws_needed(4)) bsl = 4;
  const int nsl = BB / bsl;

  const size_t Es = (size_t)bsl * SS * DD;
  const size_t Ms = (size_t)bsl * SS;
  char* p = (char*)d_ws;
  bf16* proj  = (bf16*)p; p += Ms * NPROJ * 2;
  bf16* phib  = (bf16*)p; p += Es * 2;
  float* phi  = (float*)p; p += Es * 4;
  bf16* xh    = (bf16*)p; p += Es * 2;
  bf16* ctxn  = (bf16*)p; p += 4 * Es * 2;
  float* pA   = (float*)p; p += (size_t)bsl * NCH * DD * 4;
  float* pRIM = (float*)p; p += 3 * (size_t)bsl * NCH * DD * 4;
  float* bcat = (float*)p; p += NPROJ * 4;
  bf16* WTcat = (bf16*)p; p += (size_t)NPROJ * DD * 2;
  bf16* WTp2  = (bf16*)p; p += (size_t)DD * DD * 2;
  bf16* WTo1  = (bf16*)p; p += (size_t)2048 * 1024 * 2;
  bf16* WTo2  = (bf16*)p; p += (size_t)1024 * 512 * 2;
  bf16* hh    = proj;   // [Ms,1024] overlay (proj dead when o1 runs)

  dim3 tb(256);
  dim3 tg(512);
  const size_t WD = (size_t)DD * DD;
  wtrans<<<dim3(16, 16), tb, 0, stream>>>(W_omega, WTcat,          DD, DD);
  wtrans<<<dim3(16, 16), tb, 0, stream>>>(W_gate,  WTcat + WD,     DD, DD);
  wtrans<<<dim3(16, 16), tb, 0, stream>>>(W_mag,   WTcat + 2 * WD, DD, DD);
  wtrans<<<dim3(16, 16), tb, 0, stream>>>(W_p1,    WTcat + 3 * WD, DD, DD);
  wtrans<<<dim3(16, 16), tb, 0, stream>>>(W_qoff,  WTcat + 4 * WD, DD, DD);
  wtrans<<<dim3(16, 16), tb, 0, stream>>>(W_p2,    WTp2, DD, DD);
  wtrans<<<dim3(32, 64), tb, 0, stream>>>(W_o1,    WTo1, 4 * DD, 2 * DD);
  wtrans<<<dim3(16, 32), tb, 0, stream>>>(W_o2,    WTo2, 2 * DD, DD);
  bconcat<<<5, DD, 0, stream>>>(b_omega, b_gate, b_mag, b_p1, b_qoff, bcat);

  const int gyM = (int)(Ms / 128);             // 64 / 128 / 256 (div by 8)
  const dim3 gP(NPROJ / 256, gyM);             // (10, gyM)
  const dim3 gD(DD / 256, gyM);                // (2, gyM)
  const dim3 gO1((2 * DD) / 256, gyM);         // (4, gyM)

  for (int sl = 0; sl < nsl; ++sl) {
    const float* xs = x + sl * Es;
    float* outs = out + sl * Es;
    castbf<<<(int)(Es / 1024), tb, 0, stream>>>(xs, xh, (int)Es);
    // fused projections + p2
    gemm_mfma<<<gP, tg, 0, stream>>>(xh, DD, WTcat, bcat, nullptr, proj, DD, NPROJ, 9, 1);
    gemm_mfma<<<gD, tg, 0, stream>>>(proj + 3 * DD, NPROJ, WTp2, b_p2, nullptr, phib, DD, DD, 0, 1);
    // scans
    scan_partialA<<<bsl * NCH, 512, 0, stream>>>(proj, iscale, pA);
    scan_excl_par<<<bsl * DD, 128, 0, stream>>>(pA);
    scan_stageB<<<bsl * NCH, 512, 0, stream>>>(proj, xh, phib, iscale, phi, pA, pRIM, bsl);
    scan_excl_par<<<3 * bsl * DD, 128, 0, stream>>>(pRIM);
    scan_final<<<bsl * NCH, 512, 0, stream>>>(proj, xh, phi, pRIM, ln_g, ln_b, ctxn, bsl);
    // output MLP
    gemm_mfma<<<gO1, tg, 0, stream>>>(ctxn, 4 * DD, WTo1, b_o1, nullptr, hh, 4 * DD, 2 * DD, 3, 1);
    gemm_mfma<<<gD, tg, 0, stream>>>(hh, 2 * DD, WTo2, b_o2, xs, outs, 2 * DD, DD, 0, 0);
  }
}